// Round 15
// baseline (199.164 us; speedup 1.0000x reference)
//
#include <hip/hip_runtime.h>
#include <math.h>

#define BB   512
#define TT   256
#define EMBD 364
#define HS   64
#define KPAD 384
#define NC   192

typedef __attribute__((ext_vector_type(8))) short short8_t;  // 8 bf16
typedef __attribute__((ext_vector_type(4))) float f32x4;

__device__ __forceinline__ ushort f2bf(float v) {
    union { float f; unsigned u; } c; c.f = v;
    unsigned b = c.u;
    return (ushort)((b + 0x7FFF + ((b >> 16) & 1)) >> 16);   // RNE
}
__device__ __forceinline__ ushort f2bfc(float v) {           // cheap round (A-frags only)
    union { float f; unsigned u; } c; c.f = v;
    return (ushort)((c.u + 0x8000u) >> 16);
}

// async global->LDS, 16B per lane: lane l writes LP + l*16 (dest wave-uniform base)
#define GLOAD_LDS16(GP, LP)                                                       \
    __builtin_amdgcn_global_load_lds(                                             \
        (const __attribute__((address_space(1))) void*)(const void*)(GP),         \
        (__attribute__((address_space(3))) void*)(void*)(LP), 16, 0, 0)

// ---------------- d_ws layout ----------------
#define WTR_BYTES ((size_t)144 * 512 * 2)            // 147456 (B-frag-ordered W)

// ---------- kernel 0: W -> B-fragment-ordered bf16 WTr, k-part pre-scaled ----------
// slot (jj, t): jj = 16-col N-tile of [k|q|v], t = K-subchunk(32). lane l, elem i:
// value = W^T[col = jj*16 + (l&15)][k = t*32 + (l>>4)*8 + i]; k >= 364 zeroed.
__global__ void prep_wtr(const float* __restrict__ Wk, const float* __restrict__ Wq,
                         const float* __restrict__ Wv, ushort* __restrict__ WTr)
{
    const int bid = blockIdx.x;          // 0..143 = jj*12 + t
    const int jj  = bid / 12;
    const int t   = bid % 12;
    const int l   = threadIdx.x;
    const int c   = jj * 16 + (l & 15);
    const float* Wp = (c < 64) ? Wk : (c < 128 ? Wq : Wv);
    const float s   = (c < 64) ? 0.125f : 1.0f;
    const int col   = c & 63;
    #pragma unroll
    for (int i = 0; i < 8; ++i) {
        int k = t * 32 + (l >> 4) * 8 + i;
        float v = (k < EMBD) ? Wp[(size_t)k * HS + col] * s : 0.f;
        WTr[((size_t)bid * 64 + l) * 8 + i] = f2bf(v);
    }
}

// ---------------- fused kernel LDS layout (bytes) ----------------
// kb[256][72]u  qb[256][72]u  vbT[64][264]u  xf[2][64*68]f (pb aliases xf, phase 2)
#define KB_B   0
#define QB_B   (KB_B  + TT * 72 * 2)     // 36864
#define VBT_B  (QB_B  + TT * 72 * 2)     // 73728
#define XF_B   (VBT_B + 64 * 264 * 2)    // 107520
#define LDS_TOTAL (XF_B + 2 * 17408)     // 142336 B < 160 KiB

// ================= Fused kernel: proj (m97-style gload_lds pipeline) + attn =================
// 512 blocks (1 batch each) x 512 thr (8 waves). Phase 1: 4 M-tiles x 6 K-chunks(64),
// x staged fp32 via width-16 global_load_lds into pitch-68 rows (bank+4/row -> 2-way, free),
// STAGE(u+1) issued BEFORE COMPUTE(u), one barrier per chunk. kqv stay in LDS.
// Phase 2: R3's proven in-LDS causal flash attention.
__global__ __launch_bounds__(512, 1) void head_fused2(
    const float* __restrict__ x, const ushort* __restrict__ WTr,
    const float* __restrict__ bk_, const float* __restrict__ bq_,
    const float* __restrict__ bv_, float* __restrict__ out)
{
    const int b   = blockIdx.x;
    const int tid = threadIdx.x;
    const int l   = tid & 63;
    const int w   = tid >> 6;          // 0..7
    const int l15 = l & 15;
    const int lg  = l >> 4;

    extern __shared__ char sm[];
    ushort* kb  = (ushort*)(sm + KB_B);
    ushort* qb  = (ushort*)(sm + QB_B);
    ushort* vbT = (ushort*)(sm + VBT_B);
    float*  xf  = (float*)(sm + XF_B);             // [2][4352]
    ushort* pbw = (ushort*)(sm + XF_B) + w * (16 * 40);   // phase 2 only (aliases xf)

    const float* xb = x + (size_t)b * TT * EMBD;

    const int nhalf = w & 1;           // N half: j-tiles nhalf*6 .. +6
    const int msub  = w >> 1;          // 16-row subtile within each 64-row M-tile

    float bias6[6];
    #pragma unroll
    for (int j = 0; j < 6; ++j) {
        int c = (nhalf * 6 + j) * 16 + l15;
        bias6[j] = (c < 64) ? bk_[c] * 0.125f : (c < 128 ? bq_[c - 64] : bv_[c - 128]);
    }

    // stage chunk (MI, KC) into buffer BUF: 17 width-16 instrs, rows pitch 17 quads (68 floats)
    // tail alignment: KC==5, p>=11 <-> k>=364, nulled by WTr's zero rows.
#define STAGE(MI, KC, BUF)                                                         \
    {                                                                              \
        for (int g = w; g < 17; g += 8) {                                          \
            int f   = g * 64 + l;                                                  \
            int row = f / 17;                                                      \
            int p   = f - row * 17;                                                \
            int col = ((p < 16) && ((KC) < 5 || p < 11)) ? ((KC) * 64 + p * 4) : 0;\
            GLOAD_LDS16(xb + (size_t)((MI) * 64 + row) * EMBD + col,               \
                        sm + XF_B + (BUF) * 17408 + g * 1024);                     \
        }                                                                          \
    }

    f32x4 acc[6];
    #pragma unroll
    for (int j = 0; j < 6; ++j) acc[j] = (f32x4){0.f, 0.f, 0.f, 0.f};

    // ================= Phase 1 =================
    STAGE(0, 0, 0);
    __syncthreads();                   // drain stage(0)

    #pragma unroll
    for (int u = 0; u < 24; ++u) {
        const int mi = u / 6, kc = u - mi * 6, buf = u & 1;
        if (u < 23) STAGE((u + 1) / 6, (u + 1) % 6, (u + 1) & 1);   // overlaps compute

        // ---- compute chunk u from buf ----
        const float* xp = xf + buf * 4352;
        short8_t af[2];
        #pragma unroll
        for (int ks = 0; ks < 2; ++ks) {
            const float* pf = xp + (msub * 16 + l15) * 68 + ks * 32 + lg * 8;
            f32x4 A0 = *(const f32x4*)pf;
            f32x4 A1 = *(const f32x4*)(pf + 4);
            union { short8_t s8; ushort us[8]; } pk;
            pk.us[0] = f2bfc(A0[0]); pk.us[1] = f2bfc(A0[1]);
            pk.us[2] = f2bfc(A0[2]); pk.us[3] = f2bfc(A0[3]);
            pk.us[4] = f2bfc(A1[0]); pk.us[5] = f2bfc(A1[1]);
            pk.us[6] = f2bfc(A1[2]); pk.us[7] = f2bfc(A1[3]);
            af[ks] = pk.s8;
        }
        #pragma unroll
        for (int j = 0; j < 6; ++j) {
            #pragma unroll
            for (int ks = 0; ks < 2; ++ks) {
                short8_t Bf = *(const short8_t*)&WTr[(((size_t)(nhalf * 6 + j) * 12 + kc * 2 + ks) * 64 + l) * 8];
                acc[j] = __builtin_amdgcn_mfma_f32_16x16x32_bf16(af[ks], Bf, acc[j], 0, 0, 0);
            }
        }

        // ---- M-tile epilogue: +bias, write bf16 kb (pre-scaled) / qb / vbT ----
        if (kc == 5) {
            #pragma unroll
            for (int j = 0; j < 6; ++j) {
                const int c = (nhalf * 6 + j) * 16 + l15;
                #pragma unroll
                for (int r = 0; r < 4; ++r) {
                    const int t = mi * 64 + msub * 16 + lg * 4 + r;
                    float val = acc[j][r] + bias6[j];
                    if (c < 64)       kb[t * 72 + c]           = f2bf(val);
                    else if (c < 128) qb[t * 72 + (c - 64)]    = f2bf(val);
                    else              vbT[(c - 128) * 264 + t] = f2bf(val);
                }
                acc[j] = (f32x4){0.f, 0.f, 0.f, 0.f};
            }
        }
        __syncthreads();               // drains stage(u+1); protects buffer reuse
    }
#undef STAGE

    // ================= Phase 2: causal flash attention (in-LDS kqv) =================
    #pragma unroll
    for (int half = 0; half < 2; ++half) {
        const int rt = half ? (15 - w) : w;     // balanced causal work: 9 chunks/wave
        const int t0 = rt * 16;

        short8_t afr[2];
        afr[0] = *(const short8_t*)&kb[(t0 + l15) * 72 + lg * 8];
        afr[1] = *(const short8_t*)&kb[(t0 + l15) * 72 + 32 + lg * 8];

        float mr[4], lr[4];
        f32x4 o[4];
        #pragma unroll
        for (int r = 0; r < 4; ++r) { mr[r] = -INFINITY; lr[r] = 0.f; }
        #pragma unroll
        for (int nt = 0; nt < 4; ++nt) o[nt] = (f32x4){0.f, 0.f, 0.f, 0.f};

        const int jd = t0 >> 5;
        for (int j = 0; j <= jd; ++j) {
            const int sb = j * 32;
            f32x4 sacc[2];
            sacc[0] = (f32x4){0.f, 0.f, 0.f, 0.f};
            sacc[1] = (f32x4){0.f, 0.f, 0.f, 0.f};
            #pragma unroll
            for (int kk = 0; kk < 2; ++kk) {
                #pragma unroll
                for (int ct = 0; ct < 2; ++ct) {
                    short8_t bfr = *(const short8_t*)&qb[(sb + ct * 16 + l15) * 72 + kk * 32 + lg * 8];
                    sacc[ct] = __builtin_amdgcn_mfma_f32_16x16x32_bf16(afr[kk], bfr, sacc[ct], 0, 0, 0);
                }
            }
            #pragma unroll
            for (int ct = 0; ct < 2; ++ct) {
                int s = sb + ct * 16 + l15;
                #pragma unroll
                for (int r = 0; r < 4; ++r) {
                    int t = t0 + lg * 4 + r;
                    if (s > t) sacc[ct][r] = -INFINITY;
                }
            }
            float p0[4], p1[4], fsc[4];
            #pragma unroll
            for (int r = 0; r < 4; ++r) {
                float mx = fmaxf(sacc[0][r], sacc[1][r]);
                mx = fmaxf(mx, __shfl_xor(mx, 1));
                mx = fmaxf(mx, __shfl_xor(mx, 2));
                mx = fmaxf(mx, __shfl_xor(mx, 4));
                mx = fmaxf(mx, __shfl_xor(mx, 8));
                float nm = fmaxf(mr[r], mx);
                fsc[r] = __expf(mr[r] - nm);
                mr[r] = nm;
                p0[r] = __expf(sacc[0][r] - nm);
                p1[r] = __expf(sacc[1][r] - nm);
                float ps = p0[r] + p1[r];
                ps += __shfl_xor(ps, 1);
                ps += __shfl_xor(ps, 2);
                ps += __shfl_xor(ps, 4);
                ps += __shfl_xor(ps, 8);
                lr[r] = lr[r] * fsc[r] + ps;
            }
            #pragma unroll
            for (int nt = 0; nt < 4; ++nt)
                #pragma unroll
                for (int r = 0; r < 4; ++r) o[nt][r] *= fsc[r];
            #pragma unroll
            for (int r = 0; r < 4; ++r) {
                pbw[(lg * 4 + r) * 40 + l15]      = f2bf(p0[r]);
                pbw[(lg * 4 + r) * 40 + 16 + l15] = f2bf(p1[r]);
            }
            short8_t pa = *(const short8_t*)&pbw[l15 * 40 + lg * 8];
            #pragma unroll
            for (int nt = 0; nt < 4; ++nt) {
                short8_t bfr = *(const short8_t*)&vbT[(nt * 16 + l15) * 264 + sb + lg * 8];
                o[nt] = __builtin_amdgcn_mfma_f32_16x16x32_bf16(pa, bfr, o[nt], 0, 0, 0);
            }
        }
        #pragma unroll
        for (int r = 0; r < 4; ++r) {
            float inv = 1.0f / lr[r];
            int t = t0 + lg * 4 + r;
            float* op = out + ((size_t)b * TT + t) * HS;
            #pragma unroll
            for (int nt = 0; nt < 4; ++nt)
                op[nt * 16 + l15] = o[nt][r] * inv;
        }
    }
}

extern "C" void kernel_launch(void* const* d_in, const int* in_sizes, int n_in,
                              void* d_out, int out_size, void* d_ws, size_t ws_size,
                              hipStream_t stream) {
    const float* x  = (const float*)d_in[0];
    const float* Wk = (const float*)d_in[1];
    const float* bk = (const float*)d_in[2];
    const float* Wq = (const float*)d_in[3];
    const float* bq = (const float*)d_in[4];
    const float* Wv = (const float*)d_in[5];
    const float* bv = (const float*)d_in[6];
    float* out = (float*)d_out;

    ushort* WTr = (ushort*)d_ws;
    prep_wtr<<<dim3(144), dim3(64), 0, stream>>>(Wk, Wq, Wv, WTr);

    hipFuncSetAttribute((const void*)head_fused2,
                        hipFuncAttributeMaxDynamicSharedMemorySize, LDS_TOTAL);
    head_fused2<<<dim3(BB), dim3(512), LDS_TOTAL, stream>>>(x, WTr, bk, bq, bv, out);
}

// Round 16
// 139.615 us; speedup vs baseline: 1.4265x; 1.4265x over previous
//
#include <hip/hip_runtime.h>
#include <math.h>

#define BB   512
#define TT   256
#define EMBD 364
#define HS   64
#define KPAD 384
#define NC   192

typedef __attribute__((ext_vector_type(8))) short short8_t;  // 8 bf16
typedef __attribute__((ext_vector_type(4))) float f32x4;

__device__ __forceinline__ ushort f2bf(float v) {
    union { float f; unsigned u; } c; c.f = v;
    unsigned b = c.u;
    return (ushort)((b + 0x7FFF + ((b >> 16) & 1)) >> 16);   // RNE
}

// async global->LDS, 16B per lane: lane l writes LP + l*16 (dest wave-uniform base)
#define GLOAD_LDS16(GP, LP)                                                       \
    __builtin_amdgcn_global_load_lds(                                             \
        (const __attribute__((address_space(1))) void*)(const void*)(GP),         \
        (__attribute__((address_space(3))) void*)(void*)(LP), 16, 0, 0)

// ---------------- d_ws layout (bytes) ----------------
#define WTR_BYTES ((size_t)144 * 512 * 2)            // 147456
#define KQ_ELEMS  ((size_t)BB * TT * HS)             // 8388608
#define K_OFF_B   (WTR_BYTES)
#define Q_OFF_B   (K_OFF_B + KQ_ELEMS * 2)
#define VT_OFF_B  (Q_OFF_B + KQ_ELEMS * 2)
#define XB_OFF_B  (VT_OFF_B + KQ_ELEMS * 2)          // 50,479,104
#define XB_BYTES  ((size_t)BB * TT * KPAD * 2)       // 100,663,296
#define WS_NEED2  (XB_OFF_B + XB_BYTES)              // ~151.1 MB

// ---------- kernel 0: W -> B-fragment-ordered bf16 WTr, k-part pre-scaled ----------
__global__ void prep_wtr(const float* __restrict__ Wk, const float* __restrict__ Wq,
                         const float* __restrict__ Wv, ushort* __restrict__ WTr)
{
    const int bid = blockIdx.x;          // 0..143 = jj*12 + t
    const int jj  = bid / 12;
    const int t   = bid % 12;
    const int l   = threadIdx.x;
    const int c   = jj * 16 + (l & 15);
    const float* Wp = (c < 64) ? Wk : (c < 128 ? Wq : Wv);
    const float s   = (c < 64) ? 0.125f : 1.0f;
    const int col   = c & 63;
    #pragma unroll
    for (int i = 0; i < 8; ++i) {
        int k = t * 32 + (l >> 4) * 8 + i;
        float v = (k < EMBD) ? Wp[(size_t)k * HS + col] * s : 0.f;   // zero pad k>=364
        WTr[((size_t)bid * 64 + l) * 8 + i] = f2bf(v);
    }
}

// ---------- kernel 1: pure streaming cast x fp32 -> Xb bf16 [131072][384], zero-padded ----------
// 4096 blocks x 256 thr; block handles 32 rows x 96 ushort4-quads. 364 = 91*4 exactly.
__global__ __launch_bounds__(256, 8) void xcast(
    const float* __restrict__ x, ushort* __restrict__ Xb)
{
    const size_t r0 = (size_t)blockIdx.x * 32;
    #pragma unroll
    for (int it = 0; it < 12; ++it) {
        int f = it * 256 + threadIdx.x;        // 0..3071
        int row = f / 96;
        int p   = f - row * 96;                // ushort4 slot
        ushort4 o;
        if (p < 91) {
            float4 v = *(const float4*)&x[(r0 + row) * EMBD + p * 4];
            o.x = f2bf(v.x); o.y = f2bf(v.y); o.z = f2bf(v.z); o.w = f2bf(v.w);
        } else {
            o.x = 0; o.y = 0; o.z = 0; o.w = 0;
        }
        *(ushort4*)&Xb[(r0 + row) * KPAD + p * 4] = o;
    }
}

// ================= Kernel A (primary): bf16 single-burst whole-K projection =================
// 4096 blocks x 256 thr (4 waves). Block: 32 M-rows, full K=384 bf16 staged in ONE burst
// of 25 width-16 global_load_lds, ONE barrier, then 72 MFMA/wave, A-frags direct b128.
// LDS [32 rows][49 quads] (pitch 784 B -> bank+4/row, 2-way = free). 24.5 KB -> 6 blk/CU.
__global__ __launch_bounds__(256, 4) void proj_bf(
    const ushort* __restrict__ Xb, const ushort* __restrict__ WTr,
    const float* __restrict__ bk_, const float* __restrict__ bq_,
    const float* __restrict__ bv_,
    ushort* __restrict__ Kg, ushort* __restrict__ Qg, ushort* __restrict__ Vt)
{
    const int blk = blockIdx.x;
    const int tid = threadIdx.x;
    const int l   = tid & 63;
    const int w   = tid >> 6;
    const int l15 = l & 15;
    const int lg  = l >> 4;

    __shared__ ushort xt[32 * 392];     // 32 rows x 49 quads x 16B = 25088 B

    const ushort* xb = Xb + (size_t)blk * 32 * KPAD;

    // ---- single-burst stage: 25 instrs (32*49=1568 quads), last one half-masked ----
    for (int g = w; g < 25; g += 4) {
        int f   = g * 64 + l;                  // quad index
        if (f < 1568) {
            int row = f / 49;
            int p   = f - row * 49;
            int col = (p < 48) ? p * 8 : 0;    // pad quad: harmless re-read, never consumed
            GLOAD_LDS16(xb + (size_t)row * KPAD + col, (char*)xt + (size_t)g * 1024);
        }
    }

    float bias3[3];
    #pragma unroll
    for (int j = 0; j < 3; ++j) {
        int c = w * 48 + j * 16 + l15;
        bias3[j] = (c < 64) ? bk_[c] * 0.125f : (c < 128 ? bq_[c - 64] : bv_[c - 128]);
    }

    f32x4 acc[2][3];
    #pragma unroll
    for (int mi = 0; mi < 2; ++mi)
        #pragma unroll
        for (int j = 0; j < 3; ++j) acc[mi][j] = (f32x4){0.f, 0.f, 0.f, 0.f};

    __syncthreads();    // single drain

    // ---- compute: 12 ks x (3 WTr + 2 frag b128 + 6 MFMA) ----
    #pragma unroll
    for (int ks = 0; ks < 12; ++ks) {
        short8_t Bf[3];
        #pragma unroll
        for (int j = 0; j < 3; ++j)
            Bf[j] = *(const short8_t*)&WTr[(((size_t)(w * 3 + j) * 12 + ks) * 64 + l) * 8];
        #pragma unroll
        for (int mi = 0; mi < 2; ++mi) {
            const int row = mi * 16 + l15;
            short8_t a = *(const short8_t*)((const char*)xt + row * 784 + (ks * 4 + lg) * 16);
            #pragma unroll
            for (int j = 0; j < 3; ++j)
                acc[mi][j] = __builtin_amdgcn_mfma_f32_16x16x32_bf16(a, Bf[j], acc[mi][j], 0, 0, 0);
        }
    }

    // ---- epilogue: +bias, K/Q row-major, V transposed per batch ----
    const int b   = blk >> 3;
    const int tl0 = (blk & 7) * 32;
    #pragma unroll
    for (int j = 0; j < 3; ++j) {
        const int c = w * 48 + j * 16 + l15;
        #pragma unroll
        for (int mi = 0; mi < 2; ++mi) {
            if (c < 64) {
                #pragma unroll
                for (int r = 0; r < 4; ++r) {
                    const size_t trow = (size_t)blk * 32 + mi * 16 + lg * 4 + r;
                    Kg[trow * HS + c] = f2bf(acc[mi][j][r] + bias3[j]);
                }
            } else if (c < 128) {
                #pragma unroll
                for (int r = 0; r < 4; ++r) {
                    const size_t trow = (size_t)blk * 32 + mi * 16 + lg * 4 + r;
                    Qg[trow * HS + (c - 64)] = f2bf(acc[mi][j][r] + bias3[j]);
                }
            } else {
                ushort4 pk;
                pk.x = f2bf(acc[mi][j][0] + bias3[j]);
                pk.y = f2bf(acc[mi][j][1] + bias3[j]);
                pk.z = f2bf(acc[mi][j][2] + bias3[j]);
                pk.w = f2bf(acc[mi][j][3] + bias3[j]);
                *(ushort4*)&Vt[((size_t)b * HS + (c - 128)) * TT + tl0 + mi * 16 + lg * 4] = pk;
            }
        }
    }
}

// ================= Kernel A (fallback, ws-small): R14 fp32 single-burst proj =================
__global__ __launch_bounds__(256, 3) void proj_f32(
    const float* __restrict__ x, const ushort* __restrict__ WTr,
    const float* __restrict__ bk_, const float* __restrict__ bq_,
    const float* __restrict__ bv_,
    ushort* __restrict__ Kg, ushort* __restrict__ Qg, ushort* __restrict__ Vt)
{
    const int blk = blockIdx.x;
    const int tid = threadIdx.x;
    const int l   = tid & 63;
    const int w   = tid >> 6;
    const int l15 = l & 15;
    const int lg  = l >> 4;

    __shared__ float xf[32 * KPAD];

    const float* xb = x + (size_t)blk * 32 * EMBD;
    #pragma unroll
    for (int gi = 0; gi < 12; ++gi) {
        const int g     = w * 12 + gi;
        const unsigned flatP = (unsigned)(g * 64 + l);
        const unsigned row   = flatP / 96u;
        const unsigned p     = flatP % 96u;
        const unsigned q     = p ^ (row & 7u);
        const unsigned colq  = (q < 91u) ? q : 0u;
        GLOAD_LDS16(xb + (size_t)row * EMBD + colq * 4u, (char*)xf + (size_t)g * 1024);
    }

    float bias3[3];
    #pragma unroll
    for (int j = 0; j < 3; ++j) {
        int c = w * 48 + j * 16 + l15;
        bias3[j] = (c < 64) ? bk_[c] * 0.125f : (c < 128 ? bq_[c - 64] : bv_[c - 128]);
    }
    f32x4 acc[2][3];
    #pragma unroll
    for (int mi = 0; mi < 2; ++mi)
        #pragma unroll
        for (int j = 0; j < 3; ++j) acc[mi][j] = (f32x4){0.f, 0.f, 0.f, 0.f};
    __syncthreads();

    #pragma unroll
    for (int ks = 0; ks < 12; ++ks) {
        short8_t Bf[3];
        #pragma unroll
        for (int j = 0; j < 3; ++j)
            Bf[j] = *(const short8_t*)&WTr[(((size_t)(w * 3 + j) * 12 + ks) * 64 + l) * 8];
        #pragma unroll
        for (int mi = 0; mi < 2; ++mi) {
            const unsigned row = mi * 16 + l15;
            const unsigned q0  = ks * 8 + lg * 2;
            const unsigned p0  = q0 ^ (row & 7u);
            const unsigned p1  = (q0 + 1u) ^ (row & 7u);
            f32x4 A0 = *(const f32x4*)&xf[row * KPAD + p0 * 4u];
            f32x4 A1 = *(const f32x4*)&xf[row * KPAD + p1 * 4u];
            union { short8_t s8; ushort us[8]; } pk;
            union { float f; unsigned u; } cv;
            cv.f = A0[0]; pk.us[0] = (ushort)((cv.u + 0x8000u) >> 16);
            cv.f = A0[1]; pk.us[1] = (ushort)((cv.u + 0x8000u) >> 16);
            cv.f = A0[2]; pk.us[2] = (ushort)((cv.u + 0x8000u) >> 16);
            cv.f = A0[3]; pk.us[3] = (ushort)((cv.u + 0x8000u) >> 16);
            cv.f = A1[0]; pk.us[4] = (ushort)((cv.u + 0x8000u) >> 16);
            cv.f = A1[1]; pk.us[5] = (ushort)((cv.u + 0x8000u) >> 16);
            cv.f = A1[2]; pk.us[6] = (ushort)((cv.u + 0x8000u) >> 16);
            cv.f = A1[3]; pk.us[7] = (ushort)((cv.u + 0x8000u) >> 16);
            #pragma unroll
            for (int j = 0; j < 3; ++j)
                acc[mi][j] = __builtin_amdgcn_mfma_f32_16x16x32_bf16(pk.s8, Bf[j], acc[mi][j], 0, 0, 0);
        }
    }

    const int b   = blk >> 3;
    const int tl0 = (blk & 7) * 32;
    #pragma unroll
    for (int j = 0; j < 3; ++j) {
        const int c = w * 48 + j * 16 + l15;
        #pragma unroll
        for (int mi = 0; mi < 2; ++mi) {
            if (c < 64) {
                #pragma unroll
                for (int r = 0; r < 4; ++r) {
                    const size_t trow = (size_t)blk * 32 + mi * 16 + lg * 4 + r;
                    Kg[trow * HS + c] = f2bf(acc[mi][j][r] + bias3[j]);
                }
            } else if (c < 128) {
                #pragma unroll
                for (int r = 0; r < 4; ++r) {
                    const size_t trow = (size_t)blk * 32 + mi * 16 + lg * 4 + r;
                    Qg[trow * HS + (c - 64)] = f2bf(acc[mi][j][r] + bias3[j]);
                }
            } else {
                ushort4 pk;
                pk.x = f2bf(acc[mi][j][0] + bias3[j]);
                pk.y = f2bf(acc[mi][j][1] + bias3[j]);
                pk.z = f2bf(acc[mi][j][2] + bias3[j]);
                pk.w = f2bf(acc[mi][j][3] + bias3[j]);
                *(ushort4*)&Vt[((size_t)b * HS + (c - 128)) * TT + tl0 + mi * 16 + lg * 4] = pk;
            }
        }
    }
}

// ================= Kernel B: per-batch causal flash attention, no barriers =================
__global__ __launch_bounds__(512, 4) void attn_fused(
    const ushort* __restrict__ Kg, const ushort* __restrict__ Qg,
    const ushort* __restrict__ Vt, float* __restrict__ out)
{
    const int b   = blockIdx.x;
    const int tid = threadIdx.x;
    const int l   = tid & 63;
    const int w   = tid >> 6;
    const int l15 = l & 15;
    const int lg  = l >> 4;

    __shared__ ushort pb[8][16 * 40];
    ushort* pbw = pb[w];

    const ushort* Kb = Kg + (size_t)b * TT * HS;
    const ushort* Qb = Qg + (size_t)b * TT * HS;
    const ushort* Vb = Vt + (size_t)b * HS * TT;

    #pragma unroll
    for (int half = 0; half < 2; ++half) {
        const int rt = half ? (15 - w) : w;
        const int t0 = rt * 16;

        short8_t afr[2];
        afr[0] = *(const short8_t*)&Kb[(t0 + l15) * HS + lg * 8];
        afr[1] = *(const short8_t*)&Kb[(t0 + l15) * HS + 32 + lg * 8];

        float mr[4], lr[4];
        f32x4 o[4];
        #pragma unroll
        for (int r = 0; r < 4; ++r) { mr[r] = -INFINITY; lr[r] = 0.f; }
        #pragma unroll
        for (int nt = 0; nt < 4; ++nt) o[nt] = (f32x4){0.f, 0.f, 0.f, 0.f};

        const int jd = t0 >> 5;
        for (int j = 0; j <= jd; ++j) {
            const int sb = j * 32;
            f32x4 sacc[2];
            sacc[0] = (f32x4){0.f, 0.f, 0.f, 0.f};
            sacc[1] = (f32x4){0.f, 0.f, 0.f, 0.f};
            #pragma unroll
            for (int kk = 0; kk < 2; ++kk) {
                #pragma unroll
                for (int ct = 0; ct < 2; ++ct) {
                    short8_t bfr = *(const short8_t*)&Qb[(sb + ct * 16 + l15) * HS + kk * 32 + lg * 8];
                    sacc[ct] = __builtin_amdgcn_mfma_f32_16x16x32_bf16(afr[kk], bfr, sacc[ct], 0, 0, 0);
                }
            }
            #pragma unroll
            for (int ct = 0; ct < 2; ++ct) {
                int s = sb + ct * 16 + l15;
                #pragma unroll
                for (int r = 0; r < 4; ++r) {
                    int t = t0 + lg * 4 + r;
                    if (s > t) sacc[ct][r] = -INFINITY;
                }
            }
            float p0[4], p1[4], fsc[4];
            #pragma unroll
            for (int r = 0; r < 4; ++r) {
                float mx = fmaxf(sacc[0][r], sacc[1][r]);
                mx = fmaxf(mx, __shfl_xor(mx, 1));
                mx = fmaxf(mx, __shfl_xor(mx, 2));
                mx = fmaxf(mx, __shfl_xor(mx, 4));
                mx = fmaxf(mx, __shfl_xor(mx, 8));
                float nm = fmaxf(mr[r], mx);
                fsc[r] = __expf(mr[r] - nm);
                mr[r] = nm;
                p0[r] = __expf(sacc[0][r] - nm);
                p1[r] = __expf(sacc[1][r] - nm);
                float ps = p0[r] + p1[r];
                ps += __shfl_xor(ps, 1);
                ps += __shfl_xor(ps, 2);
                ps += __shfl_xor(ps, 4);
                ps += __shfl_xor(ps, 8);
                lr[r] = lr[r] * fsc[r] + ps;
            }
            #pragma unroll
            for (int nt = 0; nt < 4; ++nt)
                #pragma unroll
                for (int r = 0; r < 4; ++r) o[nt][r] *= fsc[r];
            #pragma unroll
            for (int r = 0; r < 4; ++r) {
                pbw[(lg * 4 + r) * 40 + l15]      = f2bf(p0[r]);
                pbw[(lg * 4 + r) * 40 + 16 + l15] = f2bf(p1[r]);
            }
            short8_t pa = *(const short8_t*)&pbw[l15 * 40 + lg * 8];
            #pragma unroll
            for (int nt = 0; nt < 4; ++nt) {
                short8_t bfr = *(const short8_t*)&Vb[(nt * 16 + l15) * TT + sb + lg * 8];
                o[nt] = __builtin_amdgcn_mfma_f32_16x16x32_bf16(pa, bfr, o[nt], 0, 0, 0);
            }
        }
        #pragma unroll
        for (int r = 0; r < 4; ++r) {
            float inv = 1.0f / lr[r];
            int t = t0 + lg * 4 + r;
            float* op = out + ((size_t)b * TT + t) * HS;
            #pragma unroll
            for (int nt = 0; nt < 4; ++nt)
                op[nt * 16 + l15] = o[nt][r] * inv;
        }
    }
}

extern "C" void kernel_launch(void* const* d_in, const int* in_sizes, int n_in,
                              void* d_out, int out_size, void* d_ws, size_t ws_size,
                              hipStream_t stream) {
    const float* x  = (const float*)d_in[0];
    const float* Wk = (const float*)d_in[1];
    const float* bk = (const float*)d_in[2];
    const float* Wq = (const float*)d_in[3];
    const float* bq = (const float*)d_in[4];
    const float* Wv = (const float*)d_in[5];
    const float* bv = (const float*)d_in[6];
    float* out = (float*)d_out;

    ushort* WTr = (ushort*)d_ws;
    ushort* Kg  = (ushort*)((char*)d_ws + K_OFF_B);
    ushort* Qg  = (ushort*)((char*)d_ws + Q_OFF_B);
    ushort* Vt  = (ushort*)((char*)d_ws + VT_OFF_B);

    prep_wtr<<<dim3(144), dim3(64), 0, stream>>>(Wk, Wq, Wv, WTr);

    if (ws_size >= WS_NEED2) {
        ushort* Xb = (ushort*)((char*)d_ws + XB_OFF_B);
        xcast<<<dim3(4096), dim3(256), 0, stream>>>(x, Xb);
        proj_bf<<<dim3(4096), dim3(256), 0, stream>>>(Xb, WTr, bk, bq, bv, Kg, Qg, Vt);
    } else {
        proj_f32<<<dim3(4096), dim3(256), 0, stream>>>(x, WTr, bk, bq, bv, Kg, Qg, Vt);
    }
    attn_fused<<<dim3(BB), dim3(512), 0, stream>>>(Kg, Qg, Vt, out);
}

// Round 17
// 109.808 us; speedup vs baseline: 1.8137x; 1.2714x over previous
//
#include <hip/hip_runtime.h>
#include <math.h>

#define BB   512
#define TT   256
#define EMBD 364
#define HS   64
#define KPAD 384
#define NC   192
#define XP   68      // fp32 LDS x-tile pitch: 68%32=4 -> conflict-free b128 frag reads

typedef __attribute__((ext_vector_type(8))) short short8_t;  // 8 bf16
typedef __attribute__((ext_vector_type(4))) float f32x4;

__device__ __forceinline__ ushort f2bf(float v) {
    union { float f; unsigned u; } c; c.f = v;
    unsigned b = c.u;
    return (ushort)((b + 0x7FFF + ((b >> 16) & 1)) >> 16);   // RNE
}
__device__ __forceinline__ ushort f2bfc(float v) {           // cheap round (A-frags only)
    union { float f; unsigned u; } c; c.f = v;
    return (ushort)((c.u + 0x8000u) >> 16);
}

// async global->LDS, 4B per lane: lane l writes LP + l*4
#define GLOAD_LDS4(GP, LP)                                                        \
    __builtin_amdgcn_global_load_lds(                                             \
        (const __attribute__((address_space(1))) void*)(const void*)(GP),         \
        (__attribute__((address_space(3))) void*)(void*)(LP), 4, 0, 0)

// ---------------- d_ws layout (bytes) ----------------
#define WTR_BYTES ((size_t)144 * 512 * 2)            // 147456 (B-frag-ordered W)
#define KQ_ELEMS  ((size_t)BB * TT * HS)             // 8388608
#define K_OFF_B   (WTR_BYTES)
#define Q_OFF_B   (K_OFF_B + KQ_ELEMS * 2)
#define VT_OFF_B  (Q_OFF_B + KQ_ELEMS * 2)

// ---------- kernel 0: W -> B-fragment-ordered bf16 WTr, k-part pre-scaled ----------
__global__ void prep_wtr(const float* __restrict__ Wk, const float* __restrict__ Wq,
                         const float* __restrict__ Wv, ushort* __restrict__ WTr)
{
    const int bid = blockIdx.x;          // 0..143 = jj*12 + t
    const int jj  = bid / 12;
    const int t   = bid % 12;
    const int l   = threadIdx.x;
    const int c   = jj * 16 + (l & 15);
    const float* Wp = (c < 64) ? Wk : (c < 128 ? Wq : Wv);
    const float s   = (c < 64) ? 0.125f : 1.0f;
    const int col   = c & 63;
    #pragma unroll
    for (int i = 0; i < 8; ++i) {
        int k = t * 32 + (l >> 4) * 8 + i;
        float v = (k < EMBD) ? Wp[(size_t)k * HS + col] * s : 0.f;
        WTr[((size_t)bid * 64 + l) * 8 + i] = f2bf(v);
    }
}

// ================= Kernel A: global_load_lds projection GEMM (R11, best measured) =================
__global__ __launch_bounds__(256, 2) void proj_gemm(
    const float* __restrict__ x, const ushort* __restrict__ WTr,
    const float* __restrict__ bk_, const float* __restrict__ bq_,
    const float* __restrict__ bv_,
    ushort* __restrict__ Kg, ushort* __restrict__ Qg, ushort* __restrict__ Vt)
{
    const int blk = blockIdx.x;
    const int tid = threadIdx.x;
    const int l   = tid & 63;
    const int w   = tid >> 6;
    const int l15 = l & 15;
    const int lg  = l >> 4;

    __shared__ float xf[2][64 * XP];    // 2 x 17408 B

    const float* xb = x + (size_t)blk * 64 * EMBD;

    float bias3[3];
    #pragma unroll
    for (int j = 0; j < 3; ++j) {
        int c = w * 48 + j * 16 + l15;
        bias3[j] = (c < 64) ? bk_[c] * 0.125f : (c < 128 ? bq_[c - 64] : bv_[c - 128]);
    }

    f32x4 acc[4][3];
    #pragma unroll
    for (int mi = 0; mi < 4; ++mi)
        #pragma unroll
        for (int j = 0; j < 3; ++j) acc[mi][j] = (f32x4){0.f, 0.f, 0.f, 0.f};

    auto STAGE = [&](int kc, int buf) {
        const int colv = kc * 64 + l;
        const int col  = (colv < EMBD) ? colv : 0;    // clamp; pads hit WTr zeros
        #pragma unroll
        for (int rr = 0; rr < 16; ++rr) {
            const int row = w * 16 + rr;
            const float* gp = xb + (size_t)row * EMBD + col;
            GLOAD_LDS4(gp, &xf[buf][row * XP]);
        }
    };

    auto COMPUTE = [&](int kc, int buf) {
        short8_t Bf[3][2];
        #pragma unroll
        for (int j = 0; j < 3; ++j)
            #pragma unroll
            for (int ks = 0; ks < 2; ++ks)
                Bf[j][ks] = *(const short8_t*)&WTr[(((size_t)(w * 3 + j) * 12 + kc * 2 + ks) * 64 + l) * 8];
        short8_t a[4][2];
        #pragma unroll
        for (int mi = 0; mi < 4; ++mi)
            #pragma unroll
            for (int ks = 0; ks < 2; ++ks) {
                const float* p = &xf[buf][(mi * 16 + l15) * XP + ks * 32 + lg * 8];
                float4 p0 = *(const float4*)p;
                float4 p1 = *(const float4*)(p + 4);
                union { short8_t s8; ushort us[8]; } pk;
                pk.us[0] = f2bfc(p0.x); pk.us[1] = f2bfc(p0.y);
                pk.us[2] = f2bfc(p0.z); pk.us[3] = f2bfc(p0.w);
                pk.us[4] = f2bfc(p1.x); pk.us[5] = f2bfc(p1.y);
                pk.us[6] = f2bfc(p1.z); pk.us[7] = f2bfc(p1.w);
                a[mi][ks] = pk.s8;
            }
        #pragma unroll
        for (int ks = 0; ks < 2; ++ks)
            #pragma unroll
            for (int mi = 0; mi < 4; ++mi)
                #pragma unroll
                for (int j = 0; j < 3; ++j)
                    acc[mi][j] = __builtin_amdgcn_mfma_f32_16x16x32_bf16(a[mi][ks], Bf[j][ks], acc[mi][j], 0, 0, 0);
    };

    STAGE(0, 0);
    __syncthreads();
    #pragma unroll
    for (int kc = 0; kc < 6; ++kc) {
        if (kc < 5) STAGE(kc + 1, (kc + 1) & 1);   // async; in flight during compute
        COMPUTE(kc, kc & 1);
        __syncthreads();                           // drains stage(kc+1) + lds reads
    }

    // ---- epilogue: +bias, K/Q row-major, V transposed per batch ----
    const int b   = blk >> 2;
    const int tl0 = (blk & 3) * 64;
    #pragma unroll
    for (int j = 0; j < 3; ++j) {
        const int c = w * 48 + j * 16 + l15;
        #pragma unroll
        for (int mi = 0; mi < 4; ++mi) {
            if (c < 64) {
                #pragma unroll
                for (int r = 0; r < 4; ++r) {
                    const size_t trow = (size_t)blk * 64 + mi * 16 + lg * 4 + r;
                    Kg[trow * HS + c] = f2bf(acc[mi][j][r] + bias3[j]);
                }
            } else if (c < 128) {
                #pragma unroll
                for (int r = 0; r < 4; ++r) {
                    const size_t trow = (size_t)blk * 64 + mi * 16 + lg * 4 + r;
                    Qg[trow * HS + (c - 64)] = f2bf(acc[mi][j][r] + bias3[j]);
                }
            } else {
                ushort4 pk;
                pk.x = f2bf(acc[mi][j][0] + bias3[j]);
                pk.y = f2bf(acc[mi][j][1] + bias3[j]);
                pk.z = f2bf(acc[mi][j][2] + bias3[j]);
                pk.w = f2bf(acc[mi][j][3] + bias3[j]);
                *(ushort4*)&Vt[((size_t)b * HS + (c - 128)) * TT + tl0 + mi * 16 + lg * 4] = pk;
            }
        }
    }
}

// ================= Kernel B: per-batch causal flash attention, no barriers =================
__global__ __launch_bounds__(512, 4) void attn_fused(
    const ushort* __restrict__ Kg, const ushort* __restrict__ Qg,
    const ushort* __restrict__ Vt, float* __restrict__ out)
{
    const int b   = blockIdx.x;
    const int tid = threadIdx.x;
    const int l   = tid & 63;
    const int w   = tid >> 6;
    const int l15 = l & 15;
    const int lg  = l >> 4;

    __shared__ ushort pb[8][16 * 40];
    ushort* pbw = pb[w];

    const ushort* Kb = Kg + (size_t)b * TT * HS;
    const ushort* Qb = Qg + (size_t)b * TT * HS;
    const ushort* Vb = Vt + (size_t)b * HS * TT;

    #pragma unroll
    for (int half = 0; half < 2; ++half) {
        const int rt = half ? (15 - w) : w;     // balanced causal work: 9 chunks/wave
        const int t0 = rt * 16;

        short8_t afr[2];
        afr[0] = *(const short8_t*)&Kb[(t0 + l15) * HS + lg * 8];
        afr[1] = *(const short8_t*)&Kb[(t0 + l15) * HS + 32 + lg * 8];

        float mr[4], lr[4];
        f32x4 o[4];
        #pragma unroll
        for (int r = 0; r < 4; ++r) { mr[r] = -INFINITY; lr[r] = 0.f; }
        #pragma unroll
        for (int nt = 0; nt < 4; ++nt) o[nt] = (f32x4){0.f, 0.f, 0.f, 0.f};

        const int jd = t0 >> 5;
        for (int j = 0; j <= jd; ++j) {
            const int sb = j * 32;
            f32x4 sacc[2];
            sacc[0] = (f32x4){0.f, 0.f, 0.f, 0.f};
            sacc[1] = (f32x4){0.f, 0.f, 0.f, 0.f};
            #pragma unroll
            for (int kk = 0; kk < 2; ++kk) {
                #pragma unroll
                for (int ct = 0; ct < 2; ++ct) {
                    short8_t bfr = *(const short8_t*)&Qb[(sb + ct * 16 + l15) * HS + kk * 32 + lg * 8];
                    sacc[ct] = __builtin_amdgcn_mfma_f32_16x16x32_bf16(afr[kk], bfr, sacc[ct], 0, 0, 0);
                }
            }
            #pragma unroll
            for (int ct = 0; ct < 2; ++ct) {
                int s = sb + ct * 16 + l15;
                #pragma unroll
                for (int r = 0; r < 4; ++r) {
                    int t = t0 + lg * 4 + r;
                    if (s > t) sacc[ct][r] = -INFINITY;
                }
            }
            float p0[4], p1[4], fsc[4];
            #pragma unroll
            for (int r = 0; r < 4; ++r) {
                float mx = fmaxf(sacc[0][r], sacc[1][r]);
                mx = fmaxf(mx, __shfl_xor(mx, 1));
                mx = fmaxf(mx, __shfl_xor(mx, 2));
                mx = fmaxf(mx, __shfl_xor(mx, 4));
                mx = fmaxf(mx, __shfl_xor(mx, 8));
                float nm = fmaxf(mr[r], mx);
                fsc[r] = __expf(mr[r] - nm);
                mr[r] = nm;
                p0[r] = __expf(sacc[0][r] - nm);
                p1[r] = __expf(sacc[1][r] - nm);
                float ps = p0[r] + p1[r];
                ps += __shfl_xor(ps, 1);
                ps += __shfl_xor(ps, 2);
                ps += __shfl_xor(ps, 4);
                ps += __shfl_xor(ps, 8);
                lr[r] = lr[r] * fsc[r] + ps;
            }
            #pragma unroll
            for (int nt = 0; nt < 4; ++nt)
                #pragma unroll
                for (int r = 0; r < 4; ++r) o[nt][r] *= fsc[r];
            #pragma unroll
            for (int r = 0; r < 4; ++r) {
                pbw[(lg * 4 + r) * 40 + l15]      = f2bf(p0[r]);
                pbw[(lg * 4 + r) * 40 + 16 + l15] = f2bf(p1[r]);
            }
            short8_t pa = *(const short8_t*)&pbw[l15 * 40 + lg * 8];
            #pragma unroll
            for (int nt = 0; nt < 4; ++nt) {
                short8_t bfr = *(const short8_t*)&Vb[(nt * 16 + l15) * TT + sb + lg * 8];
                o[nt] = __builtin_amdgcn_mfma_f32_16x16x32_bf16(pa, bfr, o[nt], 0, 0, 0);
            }
        }
        #pragma unroll
        for (int r = 0; r < 4; ++r) {
            float inv = 1.0f / lr[r];
            int t = t0 + lg * 4 + r;
            float* op = out + ((size_t)b * TT + t) * HS;
            #pragma unroll
            for (int nt = 0; nt < 4; ++nt)
                op[nt * 16 + l15] = o[nt][r] * inv;
        }
    }
}

extern "C" void kernel_launch(void* const* d_in, const int* in_sizes, int n_in,
                              void* d_out, int out_size, void* d_ws, size_t ws_size,
                              hipStream_t stream) {
    const float* x  = (const float*)d_in[0];
    const float* Wk = (const float*)d_in[1];
    const float* bk = (const float*)d_in[2];
    const float* Wq = (const float*)d_in[3];
    const float* bq = (const float*)d_in[4];
    const float* Wv = (const float*)d_in[5];
    const float* bv = (const float*)d_in[6];
    float* out = (float*)d_out;

    ushort* WTr = (ushort*)d_ws;
    ushort* Kg  = (ushort*)((char*)d_ws + K_OFF_B);
    ushort* Qg  = (ushort*)((char*)d_ws + Q_OFF_B);
    ushort* Vt  = (ushort*)((char*)d_ws + VT_OFF_B);

    prep_wtr<<<dim3(144), dim3(64), 0, stream>>>(Wk, Wq, Wv, WTr);
    proj_gemm<<<dim3(2048), dim3(256), 0, stream>>>(x, WTr, bk, bq, bv, Kg, Qg, Vt);
    attn_fused<<<dim3(BB), dim3(512), 0, stream>>>(Kg, Qg, Vt, out);
}